// Round 9
// baseline (88.629 us; speedup 1.0000x reference)
//
#include <hip/hip_runtime.h>

#define T_LEN 192

// ===========================================================================
// ---- tiled GEMM body: Y[n,o,t] = sum_c W[o,c]*X[c,t] + B[o] ---------------
// TRANSX=false: X[c,t] = Xg[(n*cstr + c)*192 + t]
// TRANSX=true : X[c,u] = Xg[(n*192 + u)*192 + c]   (At layout, transposed)
// ===========================================================================
template<bool TRANSX>
__device__ __forceinline__ void gemm_body(
    float* smem,
    const float* __restrict__ W, const float* __restrict__ B,
    const float* __restrict__ X, float* __restrict__ Y,
    int cin, int cstr, int ostr, int wnstr,
    int t0, int o0, int n, int tid)
{
  float (*Ws)[68] = (float(*)[68])smem;             // [c][o]
  float (*Xs)[68] = (float(*)[68])(smem + 64 * 68); // [c][t]
  const int to = tid >> 4, tt = tid & 15;
  float acc[4][4] = {};

  for (int c0 = 0; c0 < cin; c0 += 64) {
    __syncthreads();
#pragma unroll
    for (int l = 0; l < 4; ++l) {
      int idx = l * 256 + tid;
      int rr = idx >> 4, c4 = idx & 15;
      float4 wv = *reinterpret_cast<const float4*>(
          &W[(size_t)n * wnstr + (size_t)(o0 + rr) * cin + c0 + c4 * 4]);
      Ws[c4 * 4 + 0][rr] = wv.x; Ws[c4 * 4 + 1][rr] = wv.y;
      Ws[c4 * 4 + 2][rr] = wv.z; Ws[c4 * 4 + 3][rr] = wv.w;
      if (!TRANSX) {
        float4 xv = *reinterpret_cast<const float4*>(
            &X[((size_t)n * cstr + c0 + rr) * T_LEN + t0 + c4 * 4]);
        *reinterpret_cast<float4*>(&Xs[rr][c4 * 4]) = xv;
      } else {
        float4 xv = *reinterpret_cast<const float4*>(
            &X[((size_t)n * 192 + t0 + rr) * 192 + c0 + c4 * 4]);
        Xs[c4 * 4 + 0][rr] = xv.x; Xs[c4 * 4 + 1][rr] = xv.y;
        Xs[c4 * 4 + 2][rr] = xv.z; Xs[c4 * 4 + 3][rr] = xv.w;
      }
    }
    __syncthreads();
#pragma unroll
    for (int kk = 0; kk < 64; ++kk) {
      float4 a = *reinterpret_cast<const float4*>(&Ws[kk][to * 4]);
      float4 b = *reinterpret_cast<const float4*>(&Xs[kk][tt * 4]);
      acc[0][0] += a.x * b.x; acc[0][1] += a.x * b.y; acc[0][2] += a.x * b.z; acc[0][3] += a.x * b.w;
      acc[1][0] += a.y * b.x; acc[1][1] += a.y * b.y; acc[1][2] += a.y * b.z; acc[1][3] += a.y * b.w;
      acc[2][0] += a.z * b.x; acc[2][1] += a.z * b.y; acc[2][2] += a.z * b.z; acc[2][3] += a.z * b.w;
      acc[3][0] += a.w * b.x; acc[3][1] += a.w * b.y; acc[3][2] += a.w * b.z; acc[3][3] += a.w * b.w;
    }
  }
#pragma unroll
  for (int i = 0; i < 4; ++i) {
    float bi = B ? B[o0 + to * 4 + i] : 0.f;
    float4 v = make_float4(acc[i][0] + bi, acc[i][1] + bi, acc[i][2] + bi, acc[i][3] + bi);
    *reinterpret_cast<float4*>(
        &Y[((size_t)n * ostr + o0 + to * 4 + i) * T_LEN + t0 + tt * 4]) = v;
  }
}

// ===========================================================================
// foldA: parts[chunk][j*K+i][c'] = sum_{c in 16-chunk} wa[c,j]*wk[c,c',i]
// Barrier-free: thread = c' (256), block = (s, chunk of 16 c, j-group).
// ===========================================================================
template<int K, int JN>
__device__ __forceinline__ void foldA_body(
    const float* __restrict__ wa, const float* __restrict__ wk,
    float* __restrict__ parts, int j0, int chunk, int tid)
{
  float acc[JN][K];
#pragma unroll
  for (int jj = 0; jj < JN; ++jj)
#pragma unroll
    for (int i = 0; i < K; ++i) acc[jj][i] = 0.f;

  const int c0 = chunk * 16;
  for (int c = c0; c < c0 + 16; ++c) {
    const float* base = &wk[((size_t)c * 256 + tid) * K];
    float v[K];
#pragma unroll
    for (int i = 0; i < K; ++i) v[i] = base[i];
    float w[JN];
#pragma unroll
    for (int jj = 0; jj < JN; ++jj) w[jj] = wa[c * K + j0 + jj];
#pragma unroll
    for (int jj = 0; jj < JN; ++jj)
#pragma unroll
      for (int i = 0; i < K; ++i) acc[jj][i] += w[jj] * v[i];
  }
#pragma unroll
  for (int jj = 0; jj < JN; ++jj)
#pragma unroll
    for (int i = 0; i < K; ++i)
      parts[((size_t)chunk * K * K + (j0 + jj) * K + i) * 256 + tid] = acc[jj][i];
}

// ---- cka[s,j] = sum_c wa[c,j]*bk[c] ---------------------------------------
__device__ __forceinline__ void cka_body(
    const float* __restrict__ wa0, const float* __restrict__ bk0,
    const float* __restrict__ wa1, const float* __restrict__ bk1,
    const float* __restrict__ wa2, const float* __restrict__ bk2,
    float* __restrict__ cka, int tid)
{
  if (tid >= 21) return;
  int s, j, K; const float *wa, *bk;
  if (tid < 3)       { s = 0; j = tid;      K = 3;  wa = wa0; bk = bk0; }
  else if (tid < 10) { s = 1; j = tid - 3;  K = 7;  wa = wa1; bk = bk1; }
  else               { s = 2; j = tid - 10; K = 11; wa = wa2; bk = bk2; }
  float acc = 0.f;
  for (int c = 0; c < 128; ++c) acc += wa[c * K + j] * bk[c];
  cka[s * 11 + j] = acc;
}

// ===========================================================================
// foldB: block = (s, ji, cin-half). Stage chunk-summed WKA row in LDS
// (8 coalesced loads/thread + 1 barrier), then 256 x {coalesced wp load +
// LDS broadcast + FMA}. half==0 block also computes bpA[ji] via LDS dot.
// ===========================================================================
template<int K>
__device__ __forceinline__ void foldB_body(
    float* lds, const float* __restrict__ parts, const float* __restrict__ wp,
    const float* __restrict__ bp, float* __restrict__ wxas,
    float* __restrict__ bpA_s, int ji, int half, int tid)
{
  constexpr int KP = (K + 3) & ~3;
  constexpr int K2 = K * K;
  float s = 0.f;
#pragma unroll
  for (int ch = 0; ch < 8; ++ch)
    s += parts[((size_t)(ch * K2 + ji)) * 256 + tid];
  lds[tid] = s;
  __syncthreads();

  const int cin = half * 256 + tid;
  float acc = 0.f;
  for (int c = 0; c < 256; ++c)
    acc += lds[c] * wp[(size_t)c * 512 + cin];
  const int j = ji / K, i = ji - j * K;
  wxas[(size_t)cin * K * KP + i * KP + j] = acc;

  if (half == 0 && tid == 0) {
    float b = 0.f;
    for (int c = 0; c < 256; ++c) b += lds[c] * bp[c];
    bpA_s[j * 11 + i] = b;
  }
}

// ===========================================================================
// rcomp: rpart[n,cc,j,t] = sum_{16ch,i} WXA[c,i,j]*xpad[n,c,t+i-A]
// ===========================================================================
template<int A>
__device__ __forceinline__ void rcomp_body(
    float* smem, const float* __restrict__ x, const float* __restrict__ WXAs,
    float* __restrict__ rps, int cc, int n, int tid)
{
  constexpr int K  = 2 * A + 1;
  constexpr int KP = (K + 3) & ~3;
  constexpr int WH = 192 + 2 * A;
  constexpr int WS = 204;
  float* Xs = smem;               // 16 x 204
  float* Wl = smem + 16 * WS;     // 16 x K x KP
  const int c0 = cc * 16;

  for (int idx = tid; idx < 16 * WH; idx += 256) {
    int c = idx / WH, p = idx - c * WH;
    int tau = p - A;
    Xs[c * WS + p] = (tau >= 0 && tau < 192)
        ? x[((size_t)n * 512 + c0 + c) * 192 + tau] : 0.f;
  }
  {
    const float4* wg = reinterpret_cast<const float4*>(WXAs + (size_t)c0 * K * KP);
    float4* wl = reinterpret_cast<float4*>(Wl);
    for (int idx = tid; idx < 16 * K * KP / 4; idx += 256) wl[idx] = wg[idx];
  }
  __syncthreads();

  const int w = tid >> 6, lane = tid & 63;
  const int csub = lane >> 4, tpos = lane & 15;
  const int tb = w * 48 + tpos * 3;

  float acc[K][3];
#pragma unroll
  for (int j = 0; j < K; ++j) { acc[j][0] = 0.f; acc[j][1] = 0.f; acc[j][2] = 0.f; }

#pragma unroll
  for (int c = 0; c < 4; ++c) {
    const int ch = csub * 4 + c;
    float win[K + 2];
#pragma unroll
    for (int p = 0; p < K + 2; ++p) win[p] = Xs[ch * WS + tb + p];
    const float* wr = &Wl[ch * K * KP];
#pragma unroll
    for (int i = 0; i < K; ++i) {
#pragma unroll
      for (int j = 0; j < K; ++j) {
        float wv = wr[i * KP + j];
        acc[j][0] += wv * win[i + 0];
        acc[j][1] += wv * win[i + 1];
        acc[j][2] += wv * win[i + 2];
      }
    }
  }
#pragma unroll
  for (int j = 0; j < K; ++j) {
#pragma unroll
    for (int q = 0; q < 3; ++q) {
      float v = acc[j][q];
      v += __shfl_xor(v, 16);
      v += __shfl_xor(v, 32);
      acc[j][q] = v;
    }
  }
  if (csub == 0) {
#pragma unroll
    for (int j = 0; j < K; ++j) {
      float* dst = &rps[(((size_t)n * 32 + cc) * K + j) * 192 + tb];
      dst[0] = acc[j][0]; dst[1] = acc[j][1]; dst[2] = acc[j][2];
    }
  }
}

// ---- grouped conv (groups=32, K=3) + ReLU ---------------------------------
__device__ __forceinline__ void gconv_body(
    const float* __restrict__ hin, const float* __restrict__ w2,
    const float* __restrict__ b2, float* __restrict__ hout,
    int bx, int by, int n, int tid)
{
  const int t  = (tid & 63) + bx * 64;
  const int oc = (tid >> 6) + by * 4;
  const int g  = oc >> 3;
  float acc = b2[oc];
  for (int i = 0; i < 8; ++i) {
    const float* hrow = &hin[((size_t)n * 512 + g * 8 + i) * 192];
#pragma unroll
    for (int j = 0; j < 3; ++j) {
      int tt = t + j - 1;
      float hv = (tt >= 0 && tt < 192) ? hrow[tt] : 0.f;
      acc += w2[((size_t)oc * 8 + i) * 3 + j] * hv;
    }
  }
  hout[((size_t)n * 512 + 256 + oc) * 192 + t] = fmaxf(acc, 0.f);
}

// ---- At[n][u][t] -> Aout[n][t][u] ------------------------------------------
__device__ __forceinline__ void transpose_body(
    float* smem, const float* __restrict__ At, float* __restrict__ Aout,
    int bx, int by, int n, int tid)
{
  float (*tile)[33] = (float(*)[33])smem;
  const int xx = tid & 31, y = tid >> 5;
  for (int yy = y; yy < 32; yy += 8)
    tile[yy][xx] = At[((size_t)n * 192 + by * 32 + yy) * 192 + bx * 32 + xx];
  __syncthreads();
  for (int yy = y; yy < 32; yy += 8)
    Aout[((size_t)n * 192 + bx * 32 + yy) * 192 + by * 32 + xx] = tile[xx][yy];
}

// ===========================================================================
// K1: gemm h1 (96)  ||  foldA (48)  ||  cka (1)   = 145 blocks
// ===========================================================================
__global__ __launch_bounds__(256) void k1_kernel(
    const float* __restrict__ x, const float* __restrict__ w1,
    const float* __restrict__ b1,
    const float* __restrict__ wa0, const float* __restrict__ wk0,
    const float* __restrict__ bk0,
    const float* __restrict__ wa1, const float* __restrict__ wk1,
    const float* __restrict__ bk1,
    const float* __restrict__ wa2, const float* __restrict__ wk2,
    const float* __restrict__ bk2,
    float* __restrict__ hall, float* __restrict__ partsA,
    float* __restrict__ cka)
{
  __shared__ __align__(16) float smem[8704];
  const int bid = blockIdx.x, tid = threadIdx.x;
  if (bid < 96) {
    const int tx = bid % 3, oy = (bid / 3) % 4, n = bid / 12;
    gemm_body<false>(smem, w1, b1, x, hall, 512, 512, 512, 0,
                     tx * 64, oy * 64, n, tid);
  } else if (bid < 144) {
    const int fbid = bid - 96;            // 0..47
    const int s = fbid >> 4, sub = fbid & 15;
    const int chunk = sub >> 1, jg = sub & 1;
    if (s == 0) {
      if (jg == 0) foldA_body<3, 2>(wa0, wk0, partsA,          0, chunk, tid);
      else         foldA_body<3, 1>(wa0, wk0, partsA,          2, chunk, tid);
    } else if (s == 1) {
      if (jg == 0) foldA_body<7, 4>(wa1, wk1, partsA + 18432,  0, chunk, tid);
      else         foldA_body<7, 3>(wa1, wk1, partsA + 18432,  4, chunk, tid);
    } else {
      if (jg == 0) foldA_body<11, 6>(wa2, wk2, partsA + 118784, 0, chunk, tid);
      else         foldA_body<11, 5>(wa2, wk2, partsA + 118784, 6, chunk, tid);
    }
  } else {
    cka_body(wa0, bk0, wa1, bk1, wa2, bk2, cka, tid);
  }
}

// ===========================================================================
// K2: foldB (358, bpA inline)  ||  gconv (1536)   = 1894 blocks
// ===========================================================================
__global__ __launch_bounds__(256) void k2_kernel(
    const float* __restrict__ partsA,
    const float* __restrict__ wp0, const float* __restrict__ bp0,
    const float* __restrict__ wp1, const float* __restrict__ bp1,
    const float* __restrict__ wp2, const float* __restrict__ bp2,
    float* __restrict__ WXA, float* __restrict__ bpA,
    const float* __restrict__ w2, const float* __restrict__ b2,
    float* __restrict__ hall)
{
  __shared__ float lds[256];
  const int bid = blockIdx.x, tid = threadIdx.x;
  if (bid < 18)
    foldB_body<3>(lds, partsA, wp0, bp0, WXA, bpA,
                  bid >> 1, bid & 1, tid);
  else if (bid < 116)
    foldB_body<7>(lds, partsA + 18432, wp1, bp1, WXA + 6144, bpA + 121,
                  (bid - 18) >> 1, (bid - 18) & 1, tid);
  else if (bid < 358)
    foldB_body<11>(lds, partsA + 118784, wp2, bp2, WXA + 34816, bpA + 242,
                   (bid - 116) >> 1, (bid - 116) & 1, tid);
  else {
    const int gid = bid - 358;
    gconv_body(hall, w2, b2, hall, gid % 3, (gid / 3) % 64, gid / 192, tid);
  }
}

// ===========================================================================
// K3: rcomp (768)  ||  gemm w3 (96)   = 864 blocks
// ===========================================================================
__global__ __launch_bounds__(256) void k3_kernel(
    const float* __restrict__ x, const float* __restrict__ WXA,
    float* __restrict__ rpart,
    const float* __restrict__ hall, const float* __restrict__ w3,
    const float* __restrict__ b3, float* __restrict__ xs)
{
  __shared__ __align__(16) float smem[8704];
  const int bid = blockIdx.x, tid = threadIdx.x;
  if (bid < 768) {
    const int cc = bid % 32, n = (bid / 32) % 8, s = bid / 256;
    if (s == 0)      rcomp_body<1>(smem, x, WXA,         rpart,          cc, n, tid);
    else if (s == 1) rcomp_body<3>(smem, x, WXA + 6144,  rpart + 147456, cc, n, tid);
    else             rcomp_body<5>(smem, x, WXA + 34816, rpart + 491520, cc, n, tid);
  } else {
    const int gid = bid - 768;
    const int tx = gid % 3, oy = (gid / 3) % 4, n = gid / 12;
    gemm_body<false>(smem, w3, b3, hall + 256 * 192, xs, 256, 512, 256, 0,
                     tx * 64, oy * 64, n, tid);
  }
}

// ===========================================================================
// K4: fused rreduce+abuild at FULL parallelism (384 blocks).
// Block = (n, ublk of 4 columns). Phase A: stage the 264-value window
// rbW[s][j][w] (w = tp-(u0-A)) straight from rpart (32 chunk loads each,
// same accumulation order as old rreduce -> bit-identical). Phase B:
// wave-per-column shuffle softmax reading rbW[.] at index t+j-u0.
// ===========================================================================
__global__ __launch_bounds__(256) void k4_kernel(
    const float* __restrict__ rpart, const float* __restrict__ cka,
    const float* __restrict__ bpA,
    const float* __restrict__ ba0, const float* __restrict__ ba1,
    const float* __restrict__ ba2, float* __restrict__ At)
{
  __shared__ float rbW[264];
  const int ublk = blockIdx.x % 48, n = blockIdx.x / 48;
  const int u0 = ublk * 4;
  const int tid = threadIdx.x;

  // phase A: stage window (s0: 3j x 6w | s1: 7j x 10w | s2: 11j x 16w)
  for (int idx = tid; idx < 264; idx += 256) {
    int s, j, w;
    if (idx < 18)      { s = 0; j = idx / 6;  w = idx - j * 6; }
    else if (idx < 88) { int r = idx - 18; s = 1; j = r / 10; w = r - j * 10; }
    else               { int r = idx - 88; s = 2; j = r / 16; w = r - j * 16; }
    const int As = (s == 0) ? 1 : (s == 1) ? 3 : 5;
    const int Ks = 2 * As + 1;
    const int tp = u0 - As + w;
    float acc = 0.f;
    if (tp >= 0 && tp < 192) {
      acc = cka[s * 11 + j];
      const int roff = (s == 0) ? 0 : (s == 1) ? 147456 : 491520;
      const float* rp = rpart + roff + ((size_t)(n * 32) * Ks + j) * 192 + tp;
      const size_t cstride = (size_t)Ks * 192;
#pragma unroll 8
      for (int cc = 0; cc < 32; ++cc)
        acc += rp[cc * cstride];
      for (int i = 0; i < Ks; ++i) {
        int tau = tp + i - As;
        if (tau >= 0 && tau < 192) acc += bpA[s * 121 + j * 11 + i];
      }
    }
    rbW[idx] = acc;
  }
  __syncthreads();

  // phase B: softmax (wave per column u)
  const int w = tid >> 6, lane = tid & 63;
  const int u = u0 + w;
  const int t0 = lane * 3;
  const float b0 = ba0[0], b1 = ba1[0], b2 = ba2[0];
  float v0[3], v1[3], v2[3];
#pragma unroll
  for (int q = 0; q < 3; ++q) {
    const int t = t0 + q;
    float a0 = b0, a1 = b1, a2 = b2;
#pragma unroll
    for (int j = 0; j < 3; ++j) {           // s=0, A=1
      int tp = t + j - 1, d = tp - u;
      if (tp >= 0 && tp < 192 && d <= 1 && d >= -1)
        a0 += rbW[j * 6 + (t + j - u0)];
    }
#pragma unroll
    for (int j = 0; j < 7; ++j) {           // s=1, A=3
      int tp = t + j - 3, d = tp - u;
      if (tp >= 0 && tp < 192 && d <= 3 && d >= -3)
        a1 += rbW[18 + j * 10 + (t + j - u0)];
    }
#pragma unroll
    for (int j = 0; j < 11; ++j) {          // s=2, A=5
      int tp = t + j - 5, d = tp - u;
      if (tp >= 0 && tp < 192 && d <= 5 && d >= -5)
        a2 += rbW[88 + j * 16 + (t + j - u0)];
    }
    v0[q] = a0; v1[q] = a1; v2[q] = a2;
  }

  float m0 = fmaxf(fmaxf(v0[0], v0[1]), v0[2]);
  float m1 = fmaxf(fmaxf(v1[0], v1[1]), v1[2]);
  float m2 = fmaxf(fmaxf(v2[0], v2[1]), v2[2]);
#pragma unroll
  for (int off = 32; off > 0; off >>= 1) {
    m0 = fmaxf(m0, __shfl_xor(m0, off));
    m1 = fmaxf(m1, __shfl_xor(m1, off));
    m2 = fmaxf(m2, __shfl_xor(m2, off));
  }
  float e0[3], e1[3], e2[3];
#pragma unroll
  for (int q = 0; q < 3; ++q) {
    e0[q] = __expf(v0[q] - m0);
    e1[q] = __expf(v1[q] - m1);
    e2[q] = __expf(v2[q] - m2);
  }
  float s0 = e0[0] + e0[1] + e0[2];
  float s1 = e1[0] + e1[1] + e1[2];
  float s2 = e2[0] + e2[1] + e2[2];
#pragma unroll
  for (int off = 32; off > 0; off >>= 1) {
    s0 += __shfl_xor(s0, off);
    s1 += __shfl_xor(s1, off);
    s2 += __shfl_xor(s2, off);
  }
  const float i0 = 1.f / s0, i1 = 1.f / s1, i2 = 1.f / s2;
  float* dst = &At[((size_t)n * 192 + u) * 192 + t0];
#pragma unroll
  for (int q = 0; q < 3; ++q)
    dst[q] = e0[q] * i0 + e1[q] * i1 + e2[q] * i2;
}

// ===========================================================================
// K5: out0 = xs@A (96, At read transposed)  ||  transpose (288)
// ===========================================================================
__global__ __launch_bounds__(256) void k5_kernel(
    const float* __restrict__ xs, const float* __restrict__ At,
    float* __restrict__ out0, float* __restrict__ Aout)
{
  __shared__ __align__(16) float smem[8704];
  const int bid = blockIdx.x, tid = threadIdx.x;
  if (bid < 96) {
    const int tx = bid % 3, oy = (bid / 3) % 4, n = bid / 12;
    gemm_body<true>(smem, xs, nullptr, At, out0, 192, 0, 256, 256 * 192,
                    tx * 64, oy * 64, n, tid);
  } else {
    const int gid = bid - 96;
    transpose_body(smem, At, Aout, gid % 6, (gid / 6) % 6, gid / 36, tid);
  }
}

// ===========================================================================
extern "C" void kernel_launch(void* const* d_in, const int* in_sizes, int n_in,
                              void* d_out, int out_size, void* d_ws, size_t ws_size,
                              hipStream_t stream)
{
  const float* x   = (const float*)d_in[0];
  const float* wp0 = (const float*)d_in[1];
  const float* bp0 = (const float*)d_in[2];
  const float* wk0 = (const float*)d_in[3];
  const float* bk0 = (const float*)d_in[4];
  const float* wa0 = (const float*)d_in[5];
  const float* ba0 = (const float*)d_in[6];
  const float* wp1 = (const float*)d_in[7];
  const float* bp1 = (const float*)d_in[8];
  const float* wk1 = (const float*)d_in[9];
  const float* bk1 = (const float*)d_in[10];
  const float* wa1 = (const float*)d_in[11];
  const float* ba1 = (const float*)d_in[12];
  const float* wp2 = (const float*)d_in[13];
  const float* bp2 = (const float*)d_in[14];
  const float* wk2 = (const float*)d_in[15];
  const float* bk2 = (const float*)d_in[16];
  const float* wa2 = (const float*)d_in[17];
  const float* ba2 = (const float*)d_in[18];
  const float* w1  = (const float*)d_in[19];
  const float* b1  = (const float*)d_in[20];
  const float* w2  = (const float*)d_in[21];
  const float* b2  = (const float*)d_in[22];
  const float* w3  = (const float*)d_in[23];
  const float* b3  = (const float*)d_in[24];

  float* ws     = (float*)d_ws;
  float* hall   = ws;                         // [8][512][192]        =   786,432
  float* At     = hall   + 786432;            // [8][192][192]        =   294,912
  float* xs     = At     + 294912;            // [8][256][192]        =   393,216
  float* rpart  = xs     + 393216;            // [8][32][3+7+11][192] = 1,032,192
  float* WXA    = rpart  + 1032192;           // [512]*(12+56+132)    =   102,400
  float* bpA    = WXA    + 102400;            // [3][121]             =       384
  float* cka    = bpA    + 384;               // [3][11] (pad 64)     =        64
  float* partsA = cka    + 64;                // 8*(9+49+121)*256     =   366,592
  float* out0   = (float*)d_out;              // [8][256][192]
  float* Aout   = out0 + 8 * 256 * 192;       // [8][192][192]

  // K1: h1 = w1@x  ||  foldA partial WKA  ||  cka
  k1_kernel<<<145, 256, 0, stream>>>(
      x, w1, b1, wa0, wk0, bk0, wa1, wk1, bk1, wa2, wk2, bk2,
      hall, partsA, cka);

  // K2: foldB -> WXA, bpA  ||  grouped conv + relu (h1 -> h2)
  k2_kernel<<<358 + 1536, 256, 0, stream>>>(
      partsA, wp0, bp0, wp1, bp1, wp2, bp2, WXA, bpA, w2, b2, hall);

  // K3: banded rcomp on x  ||  xs = w3@h2
  k3_kernel<<<768 + 96, 256, 0, stream>>>(x, WXA, rpart, hall, w3, b3, xs);

  // K4: fused rreduce+softmax A-build (384 blocks, LDS window staging)
  k4_kernel<<<384, 256, 0, stream>>>(rpart, cka, bpA, ba0, ba1, ba2, At);

  // K5: out0 = xs@A (transposed At staging)  ||  Aout = At^T
  k5_kernel<<<96 + 288, 256, 0, stream>>>(xs, At, out0, Aout);
}